// Round 7
// baseline (289.409 us; speedup 1.0000x reference)
//
#include <hip/hip_runtime.h>
#include <math.h>

// ISTFT via register-resident packed real inverse FFT + LDS overlap-add.
//   B=16, T=2048, 513 bins, FFT=1024, HOP=256, out = 16 x 525056 (= 2051*256).
//   Pack (R5-verified): Z[k] = (Y[k]+C[k]) + i*W1024^k*(Y[k]-C[k]),
//     C[0]=Y[512], C[k]=conj(Y[512-k]); DC/Nyquist imag parts zeroed.
//   IDFT_512 = 8(within-lane) x 64(cross-lane):
//     u_l[m] = sum_q Z[l+64q] W8^{mq}          (in-register 8-pt, const twiddles)
//     v_l[m] = u_l[m] * e^{2pi i m l/512}      (hoisted powers)
//     z[8t+m] = sum_l v_l[m] W64^{tl}          (6 shfl_xor DIF stages, t=bitrev6(lane))
//   Lane ends holding 16 contiguous samples at n0 = 16*bitrev6(lane):
//   window (hoisted, lane-fixed) + ds_add into padded OLA, then plain store.
// R7: OWN 32->16 (2064 blocks, 17.4 KB LDS -> 8 blocks/CU) + launch_bounds(256,8)
//     to pin VGPR<=64: 32 waves/CU for latency hiding of the shfl chains.

#define BATCH  16
#define TFR    2048
#define NB     513
#define HOP    256
#define OUTLEN 525056
#define TROWS  2051
#define OWN    16
#define NBLK   129                        // ceil(2051/16)
#define OLALEN (OWN * HOP)                // 4096
#define OLAPAD (OLALEN + OLALEN / 16)     // 4352 floats = 17.4 KB

#define PIDX(n) ((n) + ((n) >> 4))

#define TWO_PI 6.2831853071795864f
#define WSCALE 8.456302966727588e-4f      // (sqrt(3)/2) / 1024

__device__ __forceinline__ float2 cadd(float2 a, float2 b){ return make_float2(a.x+b.x, a.y+b.y); }
__device__ __forceinline__ float2 csub(float2 a, float2 b){ return make_float2(a.x-b.x, a.y-b.y); }
__device__ __forceinline__ float2 cmul(float2 a, float2 b){ return make_float2(a.x*b.x - a.y*b.y, a.x*b.y + a.y*b.x); }

__global__ __launch_bounds__(256, 8)
void istft_rfft(const float2* __restrict__ stfts, float* __restrict__ out)
{
    __shared__ float ola[OLAPAD];

    const int tid  = threadIdx.x;
    const int lane = tid & 63;
    const int wave = tid >> 6;

    const int b  = blockIdx.x / NBLK;
    const int ib = blockIdx.x - b * NBLK;
    const int T0 = ib * OWN;

    for (int i = tid; i < OLAPAD; i += 256) ola[i] = 0.f;

    // ---- hoisted per-lane constants (all frame-invariant) ----
    // pack twiddles W1024^{lane+64r}
    float2 ptw[8];
    #pragma unroll
    for (int r = 0; r < 8; ++r) {
        float s, c;
        sincosf(TWO_PI * (float)(lane + 64 * r) * (1.0f / 1024.0f), &s, &c);
        ptw[r] = make_float2(c, s);
    }
    // step-2 twiddles om[m] = e^{+2pi i lane*m/512}
    float2 om[8];
    om[0] = make_float2(1.f, 0.f);
    { float s, c; sincosf(TWO_PI * (float)lane * (1.0f / 512.0f), &s, &c); om[1] = make_float2(c, s); }
    #pragma unroll
    for (int m = 2; m < 8; ++m) om[m] = cmul(om[m - 1], om[1]);
    // DIF stage twiddles (merged with identity for lower lanes), h = 32,16,8,4,2
    float2 twc[5];
    #pragma unroll
    for (int s = 0; s < 5; ++s) {
        const int h = 32 >> s;
        float sn, cs;
        sincosf(TWO_PI * (float)(lane & (h - 1)) / (float)(2 * h), &sn, &cs);
        twc[s] = (lane & h) ? make_float2(cs, sn) : make_float2(1.f, 0.f);
    }
    // output ordering + window (lane-fixed: lane holds samples n0..n0+15)
    const int brl = ((lane & 1) << 5) | ((lane & 2) << 3) | ((lane & 4) << 1)
                  | ((lane & 8) >> 1) | ((lane & 16) >> 3) | ((lane & 32) >> 5);
    const int n0 = brl * 16;
    float win[16];
    #pragma unroll
    for (int j = 0; j < 16; ++j)
        win[j] = (0.5f - 0.5f * cosf(TWO_PI * (float)(n0 + j) * (1.0f / 1024.0f))) * WSCALE;

    __syncthreads();   // ola zeroed

    const int tmin = (T0 - 3 > 0) ? T0 - 3 : 0;
    const int tmax = (T0 + OWN - 1 < TFR - 1) ? T0 + OWN - 1 : TFR - 1;
    const int srcl = (64 - lane) & 63;

    for (int t = tmin + wave; t <= tmax; t += 4) {
        const float2* Xg = stfts + (size_t)(b * TFR + t) * NB;

        // load X[0..511] into regs (coalesced 8B/lane) + X[512]
        float2 X[8];
        #pragma unroll
        for (int r = 0; r < 8; ++r) X[r] = Xg[lane + 64 * r];
        const float2 X512 = Xg[512];

        // hermitian pack -> Z (k = lane + 64r; mirror from lane 64-lane, reg 7-r)
        float2 Z[8];
        #pragma unroll
        for (int r = 0; r < 8; ++r) {
            float2 mv;
            mv.x = __shfl(X[7 - r].x, srcl);
            mv.y = __shfl(X[7 - r].y, srcl);
            const float2 fix = (r == 0) ? X512 : X[(8 - r) & 7];   // lane-0 correction
            if (lane == 0) mv = fix;
            float Yy = X[r].y, Cy = -mv.y;
            if (lane == 0 && r == 0) { Yy = 0.f; Cy = 0.f; }       // DC/Nyquist imag -> 0
            const float Sx = X[r].x + mv.x, Sy = Yy + Cy;
            const float Dx = X[r].x - mv.x, Dy = Yy - Cy;
            const float2 W = ptw[r];
            const float ex = W.x * Dx - W.y * Dy;
            const float ey = W.x * Dy + W.y * Dx;
            Z[r] = make_float2(Sx - ey, Sy + ex);
        }

        // within-lane 8-pt inverse DFT over r (u[m] = sum_q Z[q] W8^{mq})
        float2 u[8];
        {
            const float2 t0 = cadd(Z[0], Z[4]), t1 = csub(Z[0], Z[4]);
            const float2 t2 = cadd(Z[2], Z[6]), t3 = csub(Z[2], Z[6]);
            const float2 t4 = cadd(Z[1], Z[5]), t5 = csub(Z[1], Z[5]);
            const float2 t6 = cadd(Z[3], Z[7]), t7 = csub(Z[3], Z[7]);
            const float2 E0 = cadd(t0, t2), E2 = csub(t0, t2);
            const float2 E1 = make_float2(t1.x - t3.y, t1.y + t3.x);   // t1 + i t3
            const float2 E3 = make_float2(t1.x + t3.y, t1.y - t3.x);   // t1 - i t3
            const float2 O0 = cadd(t4, t6), O2 = csub(t4, t6);
            const float2 O1 = make_float2(t5.x - t7.y, t5.y + t7.x);
            const float2 O3 = make_float2(t5.x + t7.y, t5.y - t7.x);
            const float cc = 0.70710678118654752f;
            const float2 W1O1 = make_float2(cc * (O1.x - O1.y), cc * (O1.x + O1.y));
            const float2 iO2  = make_float2(-O2.y, O2.x);
            const float2 W3O3 = make_float2(cc * (-O3.x - O3.y), cc * (O3.x - O3.y));
            u[0] = cadd(E0, O0);   u[4] = csub(E0, O0);
            u[1] = cadd(E1, W1O1); u[5] = csub(E1, W1O1);
            u[2] = cadd(E2, iO2);  u[6] = csub(E2, iO2);
            u[3] = cadd(E3, W3O3); u[7] = csub(E3, W3O3);
        }
        #pragma unroll
        for (int m = 1; m < 8; ++m) u[m] = cmul(u[m], om[m]);

        // 64-pt inverse DFT across lanes: 6 DIF stages (h = 32..1)
        #pragma unroll
        for (int s = 0; s < 6; ++s) {
            const int h = 32 >> s;
            const bool lo = (lane & h) == 0;
            #pragma unroll
            for (int m = 0; m < 8; ++m) {
                const float sx = __shfl_xor(u[m].x, h);
                const float sy = __shfl_xor(u[m].y, h);
                float2 w;
                w.x = sx + (lo ? u[m].x : -u[m].x);
                w.y = sy + (lo ? u[m].y : -u[m].y);
                u[m] = (h > 1) ? cmul(w, twc[s]) : w;
            }
        }

        // lane holds z[8*brl + m] -> samples n0+2m, n0+2m+1; window + OLA
        const int base = (t - T0) * HOP + n0;       // 16-aligned chunk
        if ((unsigned)base < OLALEN) {
            const int pb = PIDX(base);              // chunk contiguous after padding
            #pragma unroll
            for (int m = 0; m < 8; ++m) {
                atomicAdd(&ola[pb + 2 * m],     u[m].x * win[2 * m]);
                atomicAdd(&ola[pb + 2 * m + 1], u[m].y * win[2 * m + 1]);
            }
        }
    }

    __syncthreads();

    // plain-store exclusive region (every out element written exactly once)
    const int ownRows = (TROWS - T0 < OWN) ? (TROWS - T0) : OWN;
    const int total   = ownRows * HOP;
    float* og = out + (size_t)b * OUTLEN + (size_t)T0 * HOP;
    for (int i = tid; i < total; i += 256)
        og[i] = ola[PIDX(i)];
}

extern "C" void kernel_launch(void* const* d_in, const int* in_sizes, int n_in,
                              void* d_out, int out_size, void* d_ws, size_t ws_size,
                              hipStream_t stream)
{
    const float2* stfts = reinterpret_cast<const float2*>(d_in[0]);
    float* out = reinterpret_cast<float*>(d_out);

    istft_rfft<<<dim3(BATCH * NBLK), dim3(256), 0, stream>>>(stfts, out);
}

// Round 8
// 222.897 us; speedup vs baseline: 1.2984x; 1.2984x over previous
//
#include <hip/hip_runtime.h>
#include <math.h>

// ISTFT via register-resident packed real inverse FFT + LDS overlap-add.
//   B=16, T=2048, 513 bins, FFT=1024, HOP=256, out = 16 x 525056 (= 2051*256).
//   Pack (R5-verified): Z[k] = (Y[k]+C[k]) + i*W1024^k*(Y[k]-C[k]),
//     C[0]=Y[512], C[k]=conj(Y[512-k]); DC/Nyquist imag parts zeroed.
//   IDFT_512 = 8(within-lane) x 64(cross-lane):
//     u_l[m] = sum_q Z[l+64q] W8^{mq}          (in-register 8-pt, const twiddles)
//     v_l[m] = u_l[m] * e^{2pi i m l/512}      (hoisted powers)
//     z[8t+m] = sum_l v_l[m] W64^{tl}          (6 shfl_xor DIF stages, t=bitrev6(lane))
//   Lane ends holding 16 contiguous samples at n0 = 16*bitrev6(lane):
//   window (hoisted, lane-fixed) + ds_add into padded OLA, then plain store.
// R8: 512-thread blocks (8 waves), OWN=32, NO waves-per-EU pin (R7's pin forced
//     VGPR 60->32 and spilled: WRITE_SIZE 33->208 MB scratch traffic).
//     4 blocks/CU (LDS 34.8 KB) x 8 waves = 32 waves/CU — HW occupancy cap
//     with the natural 60-VGPR allocation.

#define BATCH  16
#define TFR    2048
#define NB     513
#define HOP    256
#define OUTLEN 525056
#define TROWS  2051
#define OWN    32
#define NBLK   65                         // ceil(2051/32)
#define OLALEN (OWN * HOP)                // 8192
#define OLAPAD (OLALEN + OLALEN / 16)     // 8704 floats = 34.8 KB

#define NTHR   512
#define NWAVE  8

#define PIDX(n) ((n) + ((n) >> 4))

#define TWO_PI 6.2831853071795864f
#define WSCALE 8.456302966727588e-4f      // (sqrt(3)/2) / 1024

__device__ __forceinline__ float2 cadd(float2 a, float2 b){ return make_float2(a.x+b.x, a.y+b.y); }
__device__ __forceinline__ float2 csub(float2 a, float2 b){ return make_float2(a.x-b.x, a.y-b.y); }
__device__ __forceinline__ float2 cmul(float2 a, float2 b){ return make_float2(a.x*b.x - a.y*b.y, a.x*b.y + a.y*b.x); }

__global__ __launch_bounds__(NTHR)
void istft_rfft(const float2* __restrict__ stfts, float* __restrict__ out)
{
    __shared__ float ola[OLAPAD];

    const int tid  = threadIdx.x;
    const int lane = tid & 63;
    const int wave = tid >> 6;

    const int b  = blockIdx.x / NBLK;
    const int ib = blockIdx.x - b * NBLK;
    const int T0 = ib * OWN;

    for (int i = tid; i < OLAPAD; i += NTHR) ola[i] = 0.f;

    // ---- hoisted per-lane constants (all frame-invariant) ----
    // pack twiddles W1024^{lane+64r}
    float2 ptw[8];
    #pragma unroll
    for (int r = 0; r < 8; ++r) {
        float s, c;
        sincosf(TWO_PI * (float)(lane + 64 * r) * (1.0f / 1024.0f), &s, &c);
        ptw[r] = make_float2(c, s);
    }
    // step-2 twiddles om[m] = e^{+2pi i lane*m/512}
    float2 om[8];
    om[0] = make_float2(1.f, 0.f);
    { float s, c; sincosf(TWO_PI * (float)lane * (1.0f / 512.0f), &s, &c); om[1] = make_float2(c, s); }
    #pragma unroll
    for (int m = 2; m < 8; ++m) om[m] = cmul(om[m - 1], om[1]);
    // DIF stage twiddles (merged with identity for lower lanes), h = 32,16,8,4,2
    float2 twc[5];
    #pragma unroll
    for (int s = 0; s < 5; ++s) {
        const int h = 32 >> s;
        float sn, cs;
        sincosf(TWO_PI * (float)(lane & (h - 1)) / (float)(2 * h), &sn, &cs);
        twc[s] = (lane & h) ? make_float2(cs, sn) : make_float2(1.f, 0.f);
    }
    // output ordering + window (lane-fixed: lane holds samples n0..n0+15)
    const int brl = ((lane & 1) << 5) | ((lane & 2) << 3) | ((lane & 4) << 1)
                  | ((lane & 8) >> 1) | ((lane & 16) >> 3) | ((lane & 32) >> 5);
    const int n0 = brl * 16;
    float win[16];
    #pragma unroll
    for (int j = 0; j < 16; ++j)
        win[j] = (0.5f - 0.5f * cosf(TWO_PI * (float)(n0 + j) * (1.0f / 1024.0f))) * WSCALE;

    __syncthreads();   // ola zeroed

    const int tmin = (T0 - 3 > 0) ? T0 - 3 : 0;
    const int tmax = (T0 + OWN - 1 < TFR - 1) ? T0 + OWN - 1 : TFR - 1;
    const int srcl = (64 - lane) & 63;

    for (int t = tmin + wave; t <= tmax; t += NWAVE) {
        const float2* Xg = stfts + (size_t)(b * TFR + t) * NB;

        // load X[0..511] into regs (coalesced 8B/lane) + X[512]
        float2 X[8];
        #pragma unroll
        for (int r = 0; r < 8; ++r) X[r] = Xg[lane + 64 * r];
        const float2 X512 = Xg[512];

        // hermitian pack -> Z (k = lane + 64r; mirror from lane 64-lane, reg 7-r)
        float2 Z[8];
        #pragma unroll
        for (int r = 0; r < 8; ++r) {
            float2 mv;
            mv.x = __shfl(X[7 - r].x, srcl);
            mv.y = __shfl(X[7 - r].y, srcl);
            const float2 fix = (r == 0) ? X512 : X[(8 - r) & 7];   // lane-0 correction
            if (lane == 0) mv = fix;
            float Yy = X[r].y, Cy = -mv.y;
            if (lane == 0 && r == 0) { Yy = 0.f; Cy = 0.f; }       // DC/Nyquist imag -> 0
            const float Sx = X[r].x + mv.x, Sy = Yy + Cy;
            const float Dx = X[r].x - mv.x, Dy = Yy - Cy;
            const float2 W = ptw[r];
            const float ex = W.x * Dx - W.y * Dy;
            const float ey = W.x * Dy + W.y * Dx;
            Z[r] = make_float2(Sx - ey, Sy + ex);
        }

        // within-lane 8-pt inverse DFT over r (u[m] = sum_q Z[q] W8^{mq})
        float2 u[8];
        {
            const float2 t0 = cadd(Z[0], Z[4]), t1 = csub(Z[0], Z[4]);
            const float2 t2 = cadd(Z[2], Z[6]), t3 = csub(Z[2], Z[6]);
            const float2 t4 = cadd(Z[1], Z[5]), t5 = csub(Z[1], Z[5]);
            const float2 t6 = cadd(Z[3], Z[7]), t7 = csub(Z[3], Z[7]);
            const float2 E0 = cadd(t0, t2), E2 = csub(t0, t2);
            const float2 E1 = make_float2(t1.x - t3.y, t1.y + t3.x);   // t1 + i t3
            const float2 E3 = make_float2(t1.x + t3.y, t1.y - t3.x);   // t1 - i t3
            const float2 O0 = cadd(t4, t6), O2 = csub(t4, t6);
            const float2 O1 = make_float2(t5.x - t7.y, t5.y + t7.x);
            const float2 O3 = make_float2(t5.x + t7.y, t5.y - t7.x);
            const float cc = 0.70710678118654752f;
            const float2 W1O1 = make_float2(cc * (O1.x - O1.y), cc * (O1.x + O1.y));
            const float2 iO2  = make_float2(-O2.y, O2.x);
            const float2 W3O3 = make_float2(cc * (-O3.x - O3.y), cc * (O3.x - O3.y));
            u[0] = cadd(E0, O0);   u[4] = csub(E0, O0);
            u[1] = cadd(E1, W1O1); u[5] = csub(E1, W1O1);
            u[2] = cadd(E2, iO2);  u[6] = csub(E2, iO2);
            u[3] = cadd(E3, W3O3); u[7] = csub(E3, W3O3);
        }
        #pragma unroll
        for (int m = 1; m < 8; ++m) u[m] = cmul(u[m], om[m]);

        // 64-pt inverse DFT across lanes: 6 DIF stages (h = 32..1)
        #pragma unroll
        for (int s = 0; s < 6; ++s) {
            const int h = 32 >> s;
            const bool lo = (lane & h) == 0;
            #pragma unroll
            for (int m = 0; m < 8; ++m) {
                const float sx = __shfl_xor(u[m].x, h);
                const float sy = __shfl_xor(u[m].y, h);
                float2 w;
                w.x = sx + (lo ? u[m].x : -u[m].x);
                w.y = sy + (lo ? u[m].y : -u[m].y);
                u[m] = (h > 1) ? cmul(w, twc[s]) : w;
            }
        }

        // lane holds z[8*brl + m] -> samples n0+2m, n0+2m+1; window + OLA
        const int base = (t - T0) * HOP + n0;       // 16-aligned chunk
        if ((unsigned)base < OLALEN) {
            const int pb = PIDX(base);              // chunk contiguous after padding
            #pragma unroll
            for (int m = 0; m < 8; ++m) {
                atomicAdd(&ola[pb + 2 * m],     u[m].x * win[2 * m]);
                atomicAdd(&ola[pb + 2 * m + 1], u[m].y * win[2 * m + 1]);
            }
        }
    }

    __syncthreads();

    // plain-store exclusive region (every out element written exactly once)
    const int ownRows = (TROWS - T0 < OWN) ? (TROWS - T0) : OWN;
    const int total   = ownRows * HOP;
    float* og = out + (size_t)b * OUTLEN + (size_t)T0 * HOP;
    for (int i = tid; i < total; i += NTHR)
        og[i] = ola[PIDX(i)];
}

extern "C" void kernel_launch(void* const* d_in, const int* in_sizes, int n_in,
                              void* d_out, int out_size, void* d_ws, size_t ws_size,
                              hipStream_t stream)
{
    const float2* stfts = reinterpret_cast<const float2*>(d_in[0]);
    float* out = reinterpret_cast<float*>(d_out);

    istft_rfft<<<dim3(BATCH * NBLK), dim3(NTHR), 0, stream>>>(stfts, out);
}

// Round 9
// 205.958 us; speedup vs baseline: 1.4052x; 1.0822x over previous
//
#include <hip/hip_runtime.h>
#include <math.h>

// ISTFT via register-resident packed real inverse FFT + LDS overlap-add.
//   Pack (R5-verified): Z[k] = (Y[k]+C[k]) + i*W1024^k*(Y[k]-C[k]),
//     C[0]=Y[512], C[k]=conj(Y[512-k]); DC/Nyquist imag parts zeroed.
//   IDFT_512 = 8(in-lane) x 64(cross-lane DIF, t = bitrev6(lane)).
// R9: cross-lane butterflies moved OFF the DS pipe where possible:
//   h=32 via v_permlane32_swap (VALU, orientation probe-corrected),
//   h=8/2/1 via DPP (row_ror:8, quad_perm xor2/xor1), h=16/4 via shfl_xor.
//   All twiddles derived from P=e^{2pi i l/1024} by squaring + literals
//   (sign folded into butterfly: u_hi = cmul(u-p, B_{2h})) -> persistent
//   per-lane constants drop 74->16 floats (R8's hidden AGPR-parking fix).

#define BATCH  16
#define TFR    2048
#define NB     513
#define HOP    256
#define OUTLEN 525056
#define TROWS  2051
#define OWN    32
#define NBLK   65                         // ceil(2051/32)
#define OLALEN (OWN * HOP)                // 8192
#define OLAPAD (OLALEN + OLALEN / 16)     // 8704 floats = 34.8 KB

#define NTHR   512
#define NWAVE  8

#define PIDX(n) ((n) + ((n) >> 4))

#define TWO_PI 6.2831853071795864f
#define WSCALE 8.456302966727588e-4f      // (sqrt(3)/2) / 1024

__device__ __forceinline__ float2 cadd(float2 a, float2 b){ return make_float2(a.x+b.x, a.y+b.y); }
__device__ __forceinline__ float2 csub(float2 a, float2 b){ return make_float2(a.x-b.x, a.y-b.y); }
__device__ __forceinline__ float2 cmul(float2 a, float2 b){ return make_float2(a.x*b.x - a.y*b.y, a.x*b.y + a.y*b.x); }

#if __has_builtin(__builtin_amdgcn_permlane32_swap)
#define HAVE_PL32 1
__device__ __forceinline__ float plsel32(float v, bool pick0) {
    auto r = __builtin_amdgcn_permlane32_swap(
        __builtin_bit_cast(int, v), __builtin_bit_cast(int, v), false, false);
    return __builtin_bit_cast(float, pick0 ? r[0] : r[1]);
}
#else
#define HAVE_PL32 0
#endif

// DPP xor within 16-lane rows: xor1 = quad_perm{1,0,3,2}=0xB1,
// xor2 = quad_perm{2,3,0,1}=0x4E, xor8 = row_ror:8 = 0x128.
template<int CTRL>
__device__ __forceinline__ float dppf(float v) {
    return __builtin_bit_cast(float,
        __builtin_amdgcn_update_dpp(0, __builtin_bit_cast(int, v), CTRL, 0xF, 0xF, true));
}

// butterfly: lo lanes -> u+p ; hi lanes -> (u-p) * e^{2pi i l/(2h)}
//   (equals the textbook twiddle e^{2pi i (l&(h-1))/(2h)} with its (-1)^bit
//    sign absorbed into the u-p order)
__device__ __forceinline__ float2 bstep(float2 u, float2 p, bool hi, float2 W) {
    const float2 s = cadd(u, p);
    const float2 d = cmul(csub(u, p), W);
    return hi ? d : s;
}

// 16th roots for pack twiddles W1024^{l+64r} = P * e^{2pi i r/16}
__device__ __constant__ const float W16C[8] = { 1.f, 0.9238795325112867f, 0.7071067811865476f, 0.3826834323650898f,
                                                0.f,-0.3826834323650898f,-0.7071067811865476f,-0.9238795325112867f };
__device__ __constant__ const float W16S[8] = { 0.f, 0.3826834323650898f, 0.7071067811865476f, 0.9238795325112867f,
                                                1.f, 0.9238795325112867f, 0.7071067811865476f, 0.3826834323650898f };
// window literals cos/sin(2pi j/1024), j = 0..15
__device__ __constant__ const float CWT[16] = {
    1.f, 0.9999811752826011f, 0.9999247018391445f, 0.9998305817958234f,
    0.9996988186962042f, 0.9995294175010931f, 0.9993223845883495f, 0.9990777277526454f,
    0.9987954562051724f, 0.9984755805732948f, 0.9981181129001492f, 0.9977230666441916f,
    0.9972904566786902f, 0.9968202992911657f, 0.9963126121827780f, 0.9957674144676598f };
__device__ __constant__ const float SWT[16] = {
    0.f, 0.0061358846491545f, 0.0122715382857199f, 0.0184067299058048f,
    0.0245412285229123f, 0.0306748031766366f, 0.0368072229413588f, 0.0429382569349408f,
    0.0490676743274180f, 0.0551952443496899f, 0.0613207363022086f, 0.0674439195636641f,
    0.0735645635996674f, 0.0796824379714301f, 0.0857973123444399f, 0.0919089564971327f };

__global__ __launch_bounds__(NTHR)
void istft_rfft(const float2* __restrict__ stfts, float* __restrict__ out)
{
    __shared__ float ola[OLAPAD];

    const int tid  = threadIdx.x;
    const int lane = tid & 63;
    const int wave = tid >> 6;

    const int b  = blockIdx.x / NBLK;
    const int ib = blockIdx.x - b * NBLK;
    const int T0 = ib * OWN;

    for (int i = tid; i < OLAPAD; i += NTHR) ola[i] = 0.f;

    // ---- base roots; every twiddle derives from these ----
    float2 P, V;
    { float s, c; sincosf(TWO_PI * (float)lane * (1.0f/1024.0f), &s, &c); P = make_float2(c, s); }
    const int brl = ((lane & 1) << 5) | ((lane & 2) << 3) | ((lane & 4) << 1)
                  | ((lane & 8) >> 1) | ((lane & 16) >> 3) | ((lane & 32) >> 5);
    const int n0 = brl * 16;
    { float s, c; sincosf(TWO_PI * (float)n0 * (1.0f/1024.0f), &s, &c); V = make_float2(c, s); }

    const float2 Q   = cmul(P, P);        // e^{2pi i l/512}
    const float2 P4  = cmul(Q, Q);        // e^{2pi i l/256} (also om[2])
    const float2 P8  = cmul(P4, P4);      // e^{2pi i l/128} (also om[4])
    const float2 B64 = cmul(P8, P8);      // e^{2pi i l/64}
    const float2 B32 = cmul(B64, B64);
    const float2 B16 = cmul(B32, B32);
    const float2 B8c = cmul(B16, B16);
    const float2 B4c = cmul(B8c, B8c);

#if HAVE_PL32
    bool pick32;
    { auto pr = __builtin_amdgcn_permlane32_swap(lane, lane, false, false);
      pick32 = ((pr[0] == (lane & 31)) == (lane >= 32)); }
#endif
    const bool hi32 = lane >= 32;
    const bool hi16 = (lane & 16) != 0;
    const bool hi8  = (lane & 8)  != 0;
    const bool hi4  = (lane & 4)  != 0;
    const bool hi2  = (lane & 2)  != 0;
    const bool hi1  = (lane & 1)  != 0;

    __syncthreads();   // ola zeroed

    const int tmin = (T0 - 3 > 0) ? T0 - 3 : 0;
    const int tmax = (T0 + OWN - 1 < TFR - 1) ? T0 + OWN - 1 : TFR - 1;
    const int srcl = (64 - lane) & 63;

    for (int t = tmin + wave; t <= tmax; t += NWAVE) {
        const float2* Xg = stfts + (size_t)(b * TFR + t) * NB;

        float2 X[8];
        #pragma unroll
        for (int r = 0; r < 8; ++r) X[r] = Xg[lane + 64 * r];
        const float2 X512 = Xg[512];

        // hermitian pack -> Z
        float2 Z[8];
        #pragma unroll
        for (int r = 0; r < 8; ++r) {
            float2 mv;
            mv.x = __shfl(X[7 - r].x, srcl);
            mv.y = __shfl(X[7 - r].y, srcl);
            const float2 fix = (r == 0) ? X512 : X[(8 - r) & 7];   // lane-0 correction
            if (lane == 0) mv = fix;
            float Yy = X[r].y, Cy = -mv.y;
            if (lane == 0 && r == 0) { Yy = 0.f; Cy = 0.f; }       // DC/Nyquist imag -> 0
            const float Sx = X[r].x + mv.x, Sy = Yy + Cy;
            const float Dx = X[r].x - mv.x, Dy = Yy - Cy;
            const float2 W = cmul(P, make_float2(W16C[r], W16S[r]));
            const float ex = W.x * Dx - W.y * Dy;
            const float ey = W.x * Dy + W.y * Dx;
            Z[r] = make_float2(Sx - ey, Sy + ex);
        }

        // within-lane 8-pt inverse DFT over r
        float2 u[8];
        {
            const float2 t0 = cadd(Z[0], Z[4]), t1 = csub(Z[0], Z[4]);
            const float2 t2 = cadd(Z[2], Z[6]), t3 = csub(Z[2], Z[6]);
            const float2 t4 = cadd(Z[1], Z[5]), t5 = csub(Z[1], Z[5]);
            const float2 t6 = cadd(Z[3], Z[7]), t7 = csub(Z[3], Z[7]);
            const float2 E0 = cadd(t0, t2), E2 = csub(t0, t2);
            const float2 E1 = make_float2(t1.x - t3.y, t1.y + t3.x);
            const float2 E3 = make_float2(t1.x + t3.y, t1.y - t3.x);
            const float2 O0 = cadd(t4, t6), O2 = csub(t4, t6);
            const float2 O1 = make_float2(t5.x - t7.y, t5.y + t7.x);
            const float2 O3 = make_float2(t5.x + t7.y, t5.y - t7.x);
            const float cc = 0.70710678118654752f;
            const float2 W1O1 = make_float2(cc * (O1.x - O1.y), cc * (O1.x + O1.y));
            const float2 iO2  = make_float2(-O2.y, O2.x);
            const float2 W3O3 = make_float2(cc * (-O3.x - O3.y), cc * (O3.x - O3.y));
            u[0] = cadd(E0, O0);   u[4] = csub(E0, O0);
            u[1] = cadd(E1, W1O1); u[5] = csub(E1, W1O1);
            u[2] = cadd(E2, iO2);  u[6] = csub(E2, iO2);
            u[3] = cadd(E3, W3O3); u[7] = csub(E3, W3O3);
        }
        // om[m] = Q^m (om2=P4, om4=P8 already persistent)
        {
            const float2 om3 = cmul(P4, Q);
            const float2 om5 = cmul(P8, Q);
            const float2 om6 = cmul(P8, P4);
            const float2 om7 = cmul(P8, om3);
            u[1] = cmul(u[1], Q);
            u[2] = cmul(u[2], P4);
            u[3] = cmul(u[3], om3);
            u[4] = cmul(u[4], P8);
            u[5] = cmul(u[5], om5);
            u[6] = cmul(u[6], om6);
            u[7] = cmul(u[7], om7);
        }

        // 64-pt cross-lane inverse DFT, 6 DIF stages
        #pragma unroll
        for (int m = 0; m < 8; ++m) {         // h=32: permlane32_swap (VALU)
            float2 p;
#if HAVE_PL32
            p = make_float2(plsel32(u[m].x, pick32), plsel32(u[m].y, pick32));
#else
            p = make_float2(__shfl_xor(u[m].x, 32), __shfl_xor(u[m].y, 32));
#endif
            u[m] = bstep(u[m], p, hi32, B64);
        }
        #pragma unroll
        for (int m = 0; m < 8; ++m) {         // h=16: shfl_xor (DS)
            const float2 p = make_float2(__shfl_xor(u[m].x, 16), __shfl_xor(u[m].y, 16));
            u[m] = bstep(u[m], p, hi16, B32);
        }
        #pragma unroll
        for (int m = 0; m < 8; ++m) {         // h=8: DPP row_ror:8 (VALU)
            const float2 p = make_float2(dppf<0x128>(u[m].x), dppf<0x128>(u[m].y));
            u[m] = bstep(u[m], p, hi8, B16);
        }
        #pragma unroll
        for (int m = 0; m < 8; ++m) {         // h=4: shfl_xor (DS)
            const float2 p = make_float2(__shfl_xor(u[m].x, 4), __shfl_xor(u[m].y, 4));
            u[m] = bstep(u[m], p, hi4, B8c);
        }
        #pragma unroll
        for (int m = 0; m < 8; ++m) {         // h=2: DPP quad_perm xor2 (VALU)
            const float2 p = make_float2(dppf<0x4E>(u[m].x), dppf<0x4E>(u[m].y));
            u[m] = bstep(u[m], p, hi2, B4c);
        }
        #pragma unroll
        for (int m = 0; m < 8; ++m) {         // h=1: DPP quad_perm xor1, no twiddle
            const float2 p = make_float2(dppf<0xB1>(u[m].x), dppf<0xB1>(u[m].y));
            u[m] = hi1 ? csub(p, u[m]) : cadd(u[m], p);
        }

        // window (from V + literals) + OLA
        const int base = (t - T0) * HOP + n0;       // 16-aligned chunk, may be <0
        if ((unsigned)base < OLALEN) {
            const int pb = PIDX(base);
            #pragma unroll
            for (int m = 0; m < 8; ++m) {
                const float w0 = 0.5f * WSCALE * (1.f - (V.x * CWT[2*m]   - V.y * SWT[2*m]));
                const float w1 = 0.5f * WSCALE * (1.f - (V.x * CWT[2*m+1] - V.y * SWT[2*m+1]));
                atomicAdd(&ola[pb + 2*m],     u[m].x * w0);
                atomicAdd(&ola[pb + 2*m + 1], u[m].y * w1);
            }
        }
    }

    __syncthreads();

    // plain-store exclusive region (every out element written exactly once)
    const int ownRows = (TROWS - T0 < OWN) ? (TROWS - T0) : OWN;
    const int total   = ownRows * HOP;
    float* og = out + (size_t)b * OUTLEN + (size_t)T0 * HOP;
    for (int i = tid; i < total; i += NTHR)
        og[i] = ola[PIDX(i)];
}

extern "C" void kernel_launch(void* const* d_in, const int* in_sizes, int n_in,
                              void* d_out, int out_size, void* d_ws, size_t ws_size,
                              hipStream_t stream)
{
    const float2* stfts = reinterpret_cast<const float2*>(d_in[0]);
    float* out = reinterpret_cast<float*>(d_out);

    istft_rfft<<<dim3(BATCH * NBLK), dim3(NTHR), 0, stream>>>(stfts, out);
}

// Round 10
// 203.913 us; speedup vs baseline: 1.4193x; 1.0100x over previous
//
#include <hip/hip_runtime.h>
#include <math.h>

// ISTFT via register-resident packed real inverse FFT + LDS overlap-add.
//   Pack (R5-verified): Z[k] = (Y[k]+C[k]) + i*W1024^k*(Y[k]-C[k]),
//     C[k]=conj(X[512-k]) (k>=1), C[0]=X[512]; DC/Nyquist imag zeroed.
//   IDFT_512 = 8(in-lane) x 64(cross-lane DIF, t = bitrev6(lane)).
// R10: DS-pipe starvation fix:
//   - pack mirror via COALESCED DESCENDING GLOBAL LOADS (Xg[512-64r-l]) ->
//     pack is pure VALU, no ds_bpermute, no lane-0 special-casing of X512.
//   - h=32/h=16 via permlane{32,16}_swap (VALU, per-lane orientation probe),
//     h=8/2/1 via DPP, h=4 via ds_swizzle 0x101F (xor4).
//   - 2-frame pairing: both frames' 32 loads issue before frame A's compute
//     (VMEM latency hides under compute; ~2x chains per wave).
//   DS ops/frame: 64 (R8) -> 24 (8 swizzle + 16 ds_add).

#define BATCH  16
#define TFR    2048
#define NB     513
#define HOP    256
#define OUTLEN 525056
#define TROWS  2051
#define OWN    32
#define NBLK   65                         // ceil(2051/32)
#define OLALEN (OWN * HOP)                // 8192
#define OLAPAD (OLALEN + OLALEN / 16)     // 8704 floats = 34.8 KB

#define NTHR   512
#define NWAVE  8

#define PIDX(n) ((n) + ((n) >> 4))

#define TWO_PI 6.2831853071795864f
#define WSCALE 8.456302966727588e-4f      // (sqrt(3)/2) / 1024

__device__ __forceinline__ float2 cadd(float2 a, float2 b){ return make_float2(a.x+b.x, a.y+b.y); }
__device__ __forceinline__ float2 csub(float2 a, float2 b){ return make_float2(a.x-b.x, a.y-b.y); }
__device__ __forceinline__ float2 cmul(float2 a, float2 b){ return make_float2(a.x*b.x - a.y*b.y, a.x*b.y + a.y*b.x); }

#if __has_builtin(__builtin_amdgcn_permlane32_swap)
#define HAVE_PL32 1
__device__ __forceinline__ float plsel32(float v, bool pick0) {
    auto r = __builtin_amdgcn_permlane32_swap(
        __builtin_bit_cast(int, v), __builtin_bit_cast(int, v), false, false);
    return __builtin_bit_cast(float, pick0 ? r[0] : r[1]);
}
#else
#define HAVE_PL32 0
#endif

#if __has_builtin(__builtin_amdgcn_permlane16_swap)
#define HAVE_PL16 1
__device__ __forceinline__ float plsel16(float v, bool pick0) {
    auto r = __builtin_amdgcn_permlane16_swap(
        __builtin_bit_cast(int, v), __builtin_bit_cast(int, v), false, false);
    return __builtin_bit_cast(float, pick0 ? r[0] : r[1]);
}
#else
#define HAVE_PL16 0
#endif

// DPP xor within 16-lane rows: xor1 = quad_perm{1,0,3,2}=0xB1,
// xor2 = quad_perm{2,3,0,1}=0x4E, xor8 = row_ror:8 = 0x128.
template<int CTRL>
__device__ __forceinline__ float dppf(float v) {
    return __builtin_bit_cast(float,
        __builtin_amdgcn_update_dpp(0, __builtin_bit_cast(int, v), CTRL, 0xF, 0xF, true));
}
// ds_swizzle BitMode xor4: offset = (4<<10)|0x1F
__device__ __forceinline__ float swz4(float v) {
    return __builtin_bit_cast(float,
        __builtin_amdgcn_ds_swizzle(__builtin_bit_cast(int, v), 0x101F));
}

// butterfly: lo lanes -> u+p ; hi lanes -> (u-p) * e^{2pi i l/(2h)}
__device__ __forceinline__ float2 bstep(float2 u, float2 p, bool hi, float2 W) {
    const float2 s = cadd(u, p);
    const float2 d = cmul(csub(u, p), W);
    return hi ? d : s;
}

// 16th roots for pack twiddles W1024^{l+64r} = P * e^{2pi i r/16}
__device__ __constant__ const float W16C[8] = { 1.f, 0.9238795325112867f, 0.7071067811865476f, 0.3826834323650898f,
                                                0.f,-0.3826834323650898f,-0.7071067811865476f,-0.9238795325112867f };
__device__ __constant__ const float W16S[8] = { 0.f, 0.3826834323650898f, 0.7071067811865476f, 0.9238795325112867f,
                                                1.f, 0.9238795325112867f, 0.7071067811865476f, 0.3826834323650898f };
// window literals cos/sin(2pi j/1024), j = 0..15
__device__ __constant__ const float CWT[16] = {
    1.f, 0.9999811752826011f, 0.9999247018391445f, 0.9998305817958234f,
    0.9996988186962042f, 0.9995294175010931f, 0.9993223845883495f, 0.9990777277526454f,
    0.9987954562051724f, 0.9984755805732948f, 0.9981181129001492f, 0.9977230666441916f,
    0.9972904566786902f, 0.9968202992911657f, 0.9963126121827780f, 0.9957674144676598f };
__device__ __constant__ const float SWT[16] = {
    0.f, 0.0061358846491545f, 0.0122715382857199f, 0.0184067299058048f,
    0.0245412285229123f, 0.0306748031766366f, 0.0368072229413588f, 0.0429382569349408f,
    0.0490676743274180f, 0.0551952443496899f, 0.0613207363022086f, 0.0674439195636641f,
    0.0735645635996674f, 0.0796824379714301f, 0.0857973123444399f, 0.0919089564971327f };

__global__ __launch_bounds__(NTHR)
void istft_rfft(const float2* __restrict__ stfts, float* __restrict__ out)
{
    __shared__ float ola[OLAPAD];

    const int tid  = threadIdx.x;
    const int lane = tid & 63;
    const int wave = tid >> 6;

    const int b  = blockIdx.x / NBLK;
    const int ib = blockIdx.x - b * NBLK;
    const int T0 = ib * OWN;

    for (int i = tid; i < OLAPAD; i += NTHR) ola[i] = 0.f;

    // ---- base roots; every twiddle derives from these ----
    float2 P, V;
    { float s, c; sincosf(TWO_PI * (float)lane * (1.0f/1024.0f), &s, &c); P = make_float2(c, s); }
    const int brl = ((lane & 1) << 5) | ((lane & 2) << 3) | ((lane & 4) << 1)
                  | ((lane & 8) >> 1) | ((lane & 16) >> 3) | ((lane & 32) >> 5);
    const int n0 = brl * 16;
    { float s, c; sincosf(TWO_PI * (float)n0 * (1.0f/1024.0f), &s, &c); V = make_float2(c, s); }

    const float2 Q   = cmul(P, P);        // e^{2pi i l/512}
    const float2 P4  = cmul(Q, Q);        // e^{2pi i l/256}
    const float2 P8  = cmul(P4, P4);      // e^{2pi i l/128}
    const float2 B64 = cmul(P8, P8);      // e^{2pi i l/64}
    const float2 B32 = cmul(B64, B64);
    const float2 B16 = cmul(B32, B32);
    const float2 B8c = cmul(B16, B16);
    const float2 B4c = cmul(B8c, B8c);

    // per-lane orientation probes (value from lane^h must be selected)
#if HAVE_PL32
    bool pick32;
    { auto pr = __builtin_amdgcn_permlane32_swap(lane, lane, false, false);
      pick32 = (pr[0] == (lane ^ 32)); }
#endif
#if HAVE_PL16
    bool pick16;
    { auto pr = __builtin_amdgcn_permlane16_swap(lane, lane, false, false);
      pick16 = (pr[0] == (lane ^ 16)); }
#endif
    const bool hi32 = lane >= 32;
    const bool hi16 = (lane & 16) != 0;
    const bool hi8  = (lane & 8)  != 0;
    const bool hi4  = (lane & 4)  != 0;
    const bool hi2  = (lane & 2)  != 0;
    const bool hi1  = (lane & 1)  != 0;

    __syncthreads();   // ola zeroed

    const int tmin = (T0 - 3 > 0) ? T0 - 3 : 0;
    const int tmax = (T0 + OWN - 1 < TFR - 1) ? T0 + OWN - 1 : TFR - 1;

    // ---- per-frame compute: pack + 512-pt IDFT + window + OLA ----
    auto frameProc = [&](const float2* X, const float2* XM, int t) {
        // hermitian pack -> Z (pure VALU; XM[r] = X[512 - (lane+64r)])
        float2 Z[8];
        #pragma unroll
        for (int r = 0; r < 8; ++r) {
            const float2 mv = XM[r];
            float Yy = X[r].y, Cy = -mv.y;
            if (lane == 0 && r == 0) { Yy = 0.f; Cy = 0.f; }   // DC/Nyquist imag -> 0
            const float Sx = X[r].x + mv.x, Sy = Yy + Cy;
            const float Dx = X[r].x - mv.x, Dy = Yy - Cy;
            const float2 W = cmul(P, make_float2(W16C[r], W16S[r]));
            const float ex = W.x * Dx - W.y * Dy;
            const float ey = W.x * Dy + W.y * Dx;
            Z[r] = make_float2(Sx - ey, Sy + ex);
        }

        // within-lane 8-pt inverse DFT over r
        float2 u[8];
        {
            const float2 t0 = cadd(Z[0], Z[4]), t1 = csub(Z[0], Z[4]);
            const float2 t2 = cadd(Z[2], Z[6]), t3 = csub(Z[2], Z[6]);
            const float2 t4 = cadd(Z[1], Z[5]), t5 = csub(Z[1], Z[5]);
            const float2 t6 = cadd(Z[3], Z[7]), t7 = csub(Z[3], Z[7]);
            const float2 E0 = cadd(t0, t2), E2 = csub(t0, t2);
            const float2 E1 = make_float2(t1.x - t3.y, t1.y + t3.x);
            const float2 E3 = make_float2(t1.x + t3.y, t1.y - t3.x);
            const float2 O0 = cadd(t4, t6), O2 = csub(t4, t6);
            const float2 O1 = make_float2(t5.x - t7.y, t5.y + t7.x);
            const float2 O3 = make_float2(t5.x + t7.y, t5.y - t7.x);
            const float cc = 0.70710678118654752f;
            const float2 W1O1 = make_float2(cc * (O1.x - O1.y), cc * (O1.x + O1.y));
            const float2 iO2  = make_float2(-O2.y, O2.x);
            const float2 W3O3 = make_float2(cc * (-O3.x - O3.y), cc * (O3.x - O3.y));
            u[0] = cadd(E0, O0);   u[4] = csub(E0, O0);
            u[1] = cadd(E1, W1O1); u[5] = csub(E1, W1O1);
            u[2] = cadd(E2, iO2);  u[6] = csub(E2, iO2);
            u[3] = cadd(E3, W3O3); u[7] = csub(E3, W3O3);
        }
        // om[m] = Q^m
        {
            const float2 om3 = cmul(P4, Q);
            const float2 om5 = cmul(P8, Q);
            const float2 om6 = cmul(P8, P4);
            const float2 om7 = cmul(P8, om3);
            u[1] = cmul(u[1], Q);
            u[2] = cmul(u[2], P4);
            u[3] = cmul(u[3], om3);
            u[4] = cmul(u[4], P8);
            u[5] = cmul(u[5], om5);
            u[6] = cmul(u[6], om6);
            u[7] = cmul(u[7], om7);
        }

        // 64-pt cross-lane inverse DFT, 6 DIF stages
        #pragma unroll
        for (int m = 0; m < 8; ++m) {         // h=32: permlane32_swap (VALU)
            float2 p;
#if HAVE_PL32
            p = make_float2(plsel32(u[m].x, pick32), plsel32(u[m].y, pick32));
#else
            p = make_float2(__shfl_xor(u[m].x, 32), __shfl_xor(u[m].y, 32));
#endif
            u[m] = bstep(u[m], p, hi32, B64);
        }
        #pragma unroll
        for (int m = 0; m < 8; ++m) {         // h=16: permlane16_swap (VALU)
            float2 p;
#if HAVE_PL16
            p = make_float2(plsel16(u[m].x, pick16), plsel16(u[m].y, pick16));
#else
            p = make_float2(__shfl_xor(u[m].x, 16), __shfl_xor(u[m].y, 16));
#endif
            u[m] = bstep(u[m], p, hi16, B32);
        }
        #pragma unroll
        for (int m = 0; m < 8; ++m) {         // h=8: DPP row_ror:8 (VALU)
            const float2 p = make_float2(dppf<0x128>(u[m].x), dppf<0x128>(u[m].y));
            u[m] = bstep(u[m], p, hi8, B16);
        }
        #pragma unroll
        for (int m = 0; m < 8; ++m) {         // h=4: ds_swizzle xor4 (DS)
            const float2 p = make_float2(swz4(u[m].x), swz4(u[m].y));
            u[m] = bstep(u[m], p, hi4, B8c);
        }
        #pragma unroll
        for (int m = 0; m < 8; ++m) {         // h=2: DPP quad_perm xor2 (VALU)
            const float2 p = make_float2(dppf<0x4E>(u[m].x), dppf<0x4E>(u[m].y));
            u[m] = bstep(u[m], p, hi2, B4c);
        }
        #pragma unroll
        for (int m = 0; m < 8; ++m) {         // h=1: DPP quad_perm xor1, no twiddle
            const float2 p = make_float2(dppf<0xB1>(u[m].x), dppf<0xB1>(u[m].y));
            u[m] = hi1 ? csub(p, u[m]) : cadd(u[m], p);
        }

        // window (from V + literals) + OLA
        const int base = (t - T0) * HOP + n0;       // 16-aligned chunk, may be <0
        if ((unsigned)base < OLALEN) {
            const int pb = PIDX(base);
            #pragma unroll
            for (int m = 0; m < 8; ++m) {
                const float w0 = 0.5f * WSCALE * (1.f - (V.x * CWT[2*m]   - V.y * SWT[2*m]));
                const float w1 = 0.5f * WSCALE * (1.f - (V.x * CWT[2*m+1] - V.y * SWT[2*m+1]));
                atomicAdd(&ola[pb + 2*m],     u[m].x * w0);
                atomicAdd(&ola[pb + 2*m + 1], u[m].y * w1);
            }
        }
    };

    // ---- main loop: 2 frames per iteration, all loads issued first ----
    for (int t = tmin + wave; t <= tmax; t += 2 * NWAVE) {
        const int  tb = t + NWAVE;
        const bool vb = (tb <= tmax);

        const float2* Ga = stfts + (size_t)(b * TFR + t) * NB;
        const float2* Gb = stfts + (size_t)(b * TFR + (vb ? tb : t)) * NB;

        float2 Xa[8], Ma[8], Xb[8], Mb[8];
        #pragma unroll
        for (int r = 0; r < 8; ++r) {
            Xa[r] = Ga[lane + 64 * r];
            Ma[r] = Ga[512 - 64 * r - lane];    // coalesced descending segment
        }
        #pragma unroll
        for (int r = 0; r < 8; ++r) {
            Xb[r] = Gb[lane + 64 * r];
            Mb[r] = Gb[512 - 64 * r - lane];
        }

        frameProc(Xa, Ma, t);
        if (vb) frameProc(Xb, Mb, tb);
    }

    __syncthreads();

    // plain-store exclusive region (every out element written exactly once)
    const int ownRows = (TROWS - T0 < OWN) ? (TROWS - T0) : OWN;
    const int total   = ownRows * HOP;
    float* og = out + (size_t)b * OUTLEN + (size_t)T0 * HOP;
    for (int i = tid; i < total; i += NTHR)
        og[i] = ola[PIDX(i)];
}

extern "C" void kernel_launch(void* const* d_in, const int* in_sizes, int n_in,
                              void* d_out, int out_size, void* d_ws, size_t ws_size,
                              hipStream_t stream)
{
    const float2* stfts = reinterpret_cast<const float2*>(d_in[0]);
    float* out = reinterpret_cast<float*>(d_out);

    istft_rfft<<<dim3(BATCH * NBLK), dim3(NTHR), 0, stream>>>(stfts, out);
}